// Round 12
// baseline (142.773 us; speedup 1.0000x reference)
//
#include <hip/hip_runtime.h>
#include <hip/hip_bf16.h>

#define BB   2
#define NNN  2048
#define DIN  256
#define HH   8
#define DHD  32
#define NW   32   // u64 mask words per row (8 groups x 4 ballot words)

typedef __attribute__((ext_vector_type(8))) short short8;
typedef __attribute__((ext_vector_type(4))) float f32x4;
typedef __attribute__((ext_vector_type(16))) float f32x16;

#if __has_builtin(__builtin_amdgcn_exp2f)
#define EXP2(x) __builtin_amdgcn_exp2f(x)
#else
#define EXP2(x) exp2f(x)
#endif

__device__ __forceinline__ unsigned int pk2(float a, float b) {
  union { __hip_bfloat162 h2; unsigned int u; } cv;
  cv.h2 = __float22bfloat162_rn(float2{a, b});   // v_cvt_pk_bf16_f32, RNE
  return cv.u;
}
__device__ __forceinline__ unsigned short f2bf(float f) {
  unsigned int u = __float_as_uint(f);
  u += 0x7fffu + ((u >> 16) & 1u);
  return (unsigned short)(u >> 16);
}

#define QSCALE (0.17677669529663687f * 1.4426950408889634f)  // 1/sqrt(32) * log2(e)

// ---------------- K0: adj -> ballot masks, max-MLP version ----------------
// 1 wave = 1 row; ALL 8 row-chunks loaded up front (8 float4 in flight/wave),
// no LDS -> full occupancy. 1024 blocks x 4 waves = 4096 waves = 16/CU.
__global__ __launch_bounds__(256) void build_mask(
    const float* __restrict__ adj, unsigned long long* __restrict__ Mk) {
  const int tid = threadIdx.x;
  const int w = tid >> 6, lane = tid & 63;
  const int row = blockIdx.x * 4 + w;
  const float* rp = adj + (size_t)row * NNN + lane * 4;

  float4 vv[8];
  #pragma unroll
  for (int G = 0; G < 8; ++G)
    vv[G] = *(const float4*)(rp + G * 256);   // all 8 issued before any use

  #pragma unroll
  for (int G = 0; G < 8; ++G) {
    unsigned long long b0 = __ballot(vv[G].x != 0.0f);
    unsigned long long b1 = __ballot(vv[G].y != 0.0f);
    unsigned long long b2 = __ballot(vv[G].z != 0.0f);
    unsigned long long b3 = __ballot(vv[G].w != 0.0f);
    if (lane < 4) {
      unsigned long long bs = (lane == 0) ? b0 : (lane == 1) ? b1 : (lane == 2) ? b2 : b3;
      Mk[(size_t)row * NW + G * 4 + lane] = bs;
    }
  }
}

// ---------------- K1: QKV gemm (W staged in LDS) + Wo cast ----------------
// [0,1536): qkv 32-out-col tiles | [1536,1600): Wo fp32 -> bf16
__global__ __launch_bounds__(256) void qkv_gemm(
    const float* __restrict__ x, const float* __restrict__ Wq,
    const float* __restrict__ Wk, const float* __restrict__ Wv,
    unsigned short* __restrict__ Qb, unsigned short* __restrict__ Kb,
    unsigned short* __restrict__ Vt,
    const float* __restrict__ Wo, unsigned short* __restrict__ Wob) {
  __shared__ __align__(16) unsigned short Wl[32][264];   // 16.9 KB
  const int bid = blockIdx.x, tid = threadIdx.x;
  const int w = tid >> 6, lane = tid & 63;

  if (bid >= 1536) {                      // ---- Wo cast ----
    int i = (bid - 1536) * 1024 + tid * 4;
    float4 v = *(const float4*)(Wo + i);
    unsigned int p[2] = {pk2(v.x, v.y), pk2(v.z, v.w)};
    *(uint2*)(Wob + i) = *(const uint2*)p;
    return;
  }
  const int y = bid >> 6, rb = bid & 63;
  const int mat = y >> 3, ocb = (y & 7) * 32;
  const float* Wsrc = ((mat == 0) ? Wq : (mat == 1) ? Wk : Wv) + (size_t)ocb * DIN;

  #pragma unroll
  for (int it = 0; it < 8; ++it) {
    int f4 = it * 256 + tid;
    int oc = f4 >> 6, k4 = f4 & 63;
    float4 v = *(const float4*)(Wsrc + (size_t)oc * DIN + k4 * 4);
    unsigned int p[2] = {pk2(v.x, v.y), pk2(v.z, v.w)};
    *(uint2*)&Wl[oc][k4 * 4] = *(const uint2*)p;
  }
  __syncthreads();

  const int col = lane & 15, quad = lane >> 4;
  const int row0 = rb * 64 + w * 16;

  f32x4 acc[2];
  #pragma unroll
  for (int c = 0; c < 2; ++c) acc[c] = (f32x4){0.f, 0.f, 0.f, 0.f};

  #pragma unroll
  for (int kk = 0; kk < 8; ++kk) {
    const float* xp = x + (size_t)(row0 + col) * DIN + kk * 32 + quad * 8;
    float4 a0 = *(const float4*)xp, a1 = *(const float4*)(xp + 4);
    union { short8 s; unsigned int u[4]; } af;
    af.u[0] = pk2(a0.x, a0.y); af.u[1] = pk2(a0.z, a0.w);
    af.u[2] = pk2(a1.x, a1.y); af.u[3] = pk2(a1.z, a1.w);
    #pragma unroll
    for (int c = 0; c < 2; ++c) {
      short8 bw = *(const short8*)&Wl[c * 16 + col][kk * 32 + quad * 8];
      acc[c] = __builtin_amdgcn_mfma_f32_16x16x32_bf16(af.s, bw, acc[c], 0, 0, 0);
    }
  }
  const float scale = (mat == 0) ? QSCALE : 1.0f;
  #pragma unroll
  for (int c = 0; c < 2; ++c) {
    int oc = ocb + c * 16 + col, h = oc >> 5, dh = oc & 31;
    #pragma unroll
    for (int r = 0; r < 4; ++r) {
      int row = row0 + quad * 4 + r;
      int b = row >> 11, n = row & (NNN - 1);
      unsigned short val = f2bf(acc[c][r] * scale);
      if (mat == 2)       Vt[((size_t)(b * HH + h) * DHD + dh) * NNN + n] = val;
      else if (mat == 0)  Qb[((size_t)(b * HH + h) * NNN + n) * DHD + dh] = val;
      else                Kb[((size_t)(b * HH + h) * NNN + n) * DHD + dh] = val;
    }
  }
}

// ---------------- K2: fused masked attention (unchanged from R11) ----------------
__global__ __launch_bounds__(512, 4) void attn(
    const unsigned short* __restrict__ Qb, const unsigned short* __restrict__ Kb,
    const unsigned short* __restrict__ Vt, const unsigned long long* __restrict__ Mk,
    unsigned short* __restrict__ AOb) {
  __shared__ float OL[8][32][33];
  __shared__ float LL[8][32];
  const int tid = threadIdx.x;
  const int w = tid >> 6, lane = tid & 63;
  const int qi = lane & 31, hi = lane >> 5;
  const int bid = blockIdx.x;
  const int xcd = bid & 7, j = bid >> 3;
  const int bh = xcd * 2 + (j >> 6);       // 2 bh per XCD
  const int qt = j & 63;
  const int b = bh >> 3, h = bh & 7;
  const int q = qt * 32 + qi;
  const int k0 = w * 256;

  const unsigned short* qp = Qb + ((size_t)bh * NNN + q) * DHD + hi * 8;
  const short8 bq0 = *(const short8*)qp;
  const short8 bq1 = *(const short8*)(qp + 16);

  f32x16 accA, accB;
  #pragma unroll
  for (int i = 0; i < 16; ++i) { accA[i] = 0.f; accB[i] = 0.f; }
  float lsum = 0.f;

  const unsigned long long* mrow = Mk + ((size_t)b * NNN + q) * NW + w * 4;
  unsigned int mlo[4], mhi2[4];
  #pragma unroll
  for (int c = 0; c < 4; ++c) {
    unsigned long long mh = mrow[c] >> hi;
    mlo[c]  = (unsigned int)mh;
    mhi2[c] = (unsigned int)(mh >> 32);
  }

  const unsigned short* kbase = Kb + ((size_t)bh * NNN + k0 + qi) * DHD + hi * 8;  // qi = key
  const unsigned short* vbase = Vt + ((size_t)bh * DHD + qi) * NNN + k0 + hi * 8;  // qi = dh

  short8 ak0 = *(const short8*)(kbase);
  short8 ak1 = *(const short8*)(kbase + 16);
  short8 av0 = *(const short8*)(vbase);
  short8 av1 = *(const short8*)(vbase + 16);

  #pragma unroll
  for (int sub = 0; sub < 8; ++sub) {
    const short8 cak0 = ak0, cak1 = ak1, cav0 = av0, cav1 = av1;
    if (sub < 7) {
      const int kn = (sub + 1) * 32;
      ak0 = *(const short8*)(kbase + (size_t)kn * DHD);
      ak1 = *(const short8*)(kbase + (size_t)kn * DHD + 16);
      av0 = *(const short8*)(vbase + kn);
      av1 = *(const short8*)(vbase + kn + 16);
    }

    f32x16 z;
    #pragma unroll
    for (int i = 0; i < 16; ++i) z[i] = 0.f;
    f32x16 st = __builtin_amdgcn_mfma_f32_32x32x16_bf16(cak0, bq0, z, 0, 0, 0);
    st = __builtin_amdgcn_mfma_f32_32x32x16_bf16(cak1, bq1, st, 0, 0, 0);

    unsigned int pk[4][2];
    float gs[4];
    #pragma unroll
    for (int g = 0; g < 4; ++g) {
      float pv[4];
      #pragma unroll
      for (int r = 0; r < 4; ++r) {
        unsigned int mwd = (sub < 4) ? mlo[r] : mhi2[r];
        const int pos = (sub & 3) * 8 + g * 2;
        int msk = ((int)(mwd << (31 - pos))) >> 31;
        float e = EXP2(st[g * 4 + r]);
        pv[r] = __uint_as_float(__float_as_uint(e) & (unsigned int)msk);
      }
      gs[g] = (pv[0] + pv[1]) + (pv[2] + pv[3]);
      pk[g][0] = pk2(pv[0], pv[1]);
      pk[g][1] = pk2(pv[2], pv[3]);
    }
    lsum += (gs[0] + gs[1]) + (gs[2] + gs[3]);

    unsigned int x00 = __shfl_xor((int)pk[0][0], 32, 64), x01 = __shfl_xor((int)pk[0][1], 32, 64);
    unsigned int x10 = __shfl_xor((int)pk[1][0], 32, 64), x11 = __shfl_xor((int)pk[1][1], 32, 64);
    unsigned int x20 = __shfl_xor((int)pk[2][0], 32, 64), x21 = __shfl_xor((int)pk[2][1], 32, 64);
    unsigned int x30 = __shfl_xor((int)pk[3][0], 32, 64), x31 = __shfl_xor((int)pk[3][1], 32, 64);

    union { short8 s; unsigned int u[4]; } F1, F2;
    F1.u[0] = hi ? x10 : pk[0][0];
    F1.u[1] = hi ? x11 : pk[0][1];
    F1.u[2] = hi ? pk[1][0] : x00;
    F1.u[3] = hi ? pk[1][1] : x01;
    F2.u[0] = hi ? x30 : pk[2][0];
    F2.u[1] = hi ? x31 : pk[2][1];
    F2.u[2] = hi ? pk[3][0] : x20;
    F2.u[3] = hi ? pk[3][1] : x21;

    accA = __builtin_amdgcn_mfma_f32_32x32x16_bf16(cav0, F1.s, accA, 0, 0, 0);
    accB = __builtin_amdgcn_mfma_f32_32x32x16_bf16(cav1, F2.s, accB, 0, 0, 0);
  }

  lsum += __shfl_xor(lsum, 32, 64);

  #pragma unroll
  for (int g = 0; g < 4; ++g)
    #pragma unroll
    for (int r = 0; r < 4; ++r)
      OL[w][qi][g * 8 + hi * 4 + r] = accA[g * 4 + r] + accB[g * 4 + r];
  if (hi == 0) LL[w][qi] = lsum;
  __syncthreads();

  const int ql = tid >> 4, c2 = (tid & 15) * 2;
  float l = 0.f, o0 = 0.f, o1 = 0.f;
  #pragma unroll
  for (int ww = 0; ww < 8; ++ww) {
    l  += LL[ww][ql];
    o0 += OL[ww][ql][c2];
    o1 += OL[ww][ql][c2 + 1];
  }
  float inv = 1.0f / l;
  unsigned int pr = pk2(o0 * inv, o1 * inv);
  *(unsigned int*)(AOb + ((size_t)(b * NNN + qt * 32 + ql)) * DIN + h * DHD + c2) = pr;
}

// ---------------- K3: output projection + bias via bf16 MFMA ----------------
// 512 blocks x 256 thr, 2 wave-tasks each (2 blocks/CU)
__global__ __launch_bounds__(256) void out_proj(const unsigned short* __restrict__ AOb,
                                                const unsigned short* __restrict__ Wob,
                                                const float* __restrict__ bo,
                                                float* __restrict__ out) {
  const int tid = threadIdx.x;
  const int lane = tid & 63, col = lane & 15, quad = lane >> 4;
  const int wv = tid >> 6;
  #pragma unroll
  for (int half = 0; half < 2; ++half) {
    const int task = blockIdx.x * 2 + half;          // 1024 tasks total
    if ((wv >> 1) != half) continue;                 // waves {0,1} -> half 0, {2,3} -> half 1
    const int sw = wv & 1;                           // 2 waves split the 4 col-blocks
    const int row0 = (task >> 2) * 16;
    const int ocb = ((task & 3)) * 64 + 0;

    f32x4 acc[4];
    #pragma unroll
    for (int c = 0; c < 4; ++c) acc[c] = (f32x4){0.f, 0.f, 0.f, 0.f};
    (void)sw;
    #pragma unroll
    for (int kk = 0; kk < 8; ++kk) {
      short8 af = *(const short8*)(AOb + (size_t)(row0 + col) * DIN + kk * 32 + quad * 8);
      #pragma unroll
      for (int c = 0; c < 4; ++c) {
        short8 bw = *(const short8*)(Wob + (size_t)(ocb + c * 16 + col) * DIN + kk * 32 + quad * 8);
        acc[c] = __builtin_amdgcn_mfma_f32_16x16x32_bf16(af, bw, acc[c], 0, 0, 0);
      }
    }
    #pragma unroll
    for (int c = 0; c < 4; ++c) {
      int oc = ocb + c * 16 + col;
      float bias = bo[oc];
      #pragma unroll
      for (int r = 0; r < 4; ++r)
        out[(size_t)(row0 + quad * 4 + r) * DIN + oc] = acc[c][r] + bias;
    }
  }
}

extern "C" void kernel_launch(void* const* d_in, const int* in_sizes, int n_in,
                              void* d_out, int out_size, void* d_ws, size_t ws_size,
                              hipStream_t stream) {
  const float* x   = (const float*)d_in[0];
  const float* adj = (const float*)d_in[1];
  const float* Wq  = (const float*)d_in[2];
  const float* Wk  = (const float*)d_in[3];
  const float* Wv  = (const float*)d_in[4];
  const float* Wo  = (const float*)d_in[5];
  const float* bo  = (const float*)d_in[6];
  float* out = (float*)d_out;

  char* ws = (char*)d_ws;
  unsigned short* Qb  = (unsigned short*)(ws);                         // 2 MB
  unsigned short* Kb  = (unsigned short*)(ws + (2ull << 20));          // 2 MB
  unsigned short* Vt  = (unsigned short*)(ws + (4ull << 20));          // 2 MB
  unsigned long long* Mk = (unsigned long long*)(ws + (6ull << 20));   // 1 MB
  unsigned short* Wob = (unsigned short*)(ws + (7ull << 20));          // 128 KB
  unsigned short* AOb = (unsigned short*)(ws + (8ull << 20));          // 2 MB

  build_mask<<<dim3(1024), 256, 0, stream>>>(adj, Mk);
  qkv_gemm<<<dim3(1600), 256, 0, stream>>>(x, Wq, Wk, Wv, Qb, Kb, Vt, Wo, Wob);
  attn<<<dim3(1024), 512, 0, stream>>>(Qb, Kb, Vt, Mk, AOb);
  out_proj<<<dim3(512), 256, 0, stream>>>(AOb, Wob, bo, out);
}

// Round 13
// 135.007 us; speedup vs baseline: 1.0575x; 1.0575x over previous
//
#include <hip/hip_runtime.h>
#include <hip/hip_bf16.h>

#define BB   2
#define NNN  2048
#define DIN  256
#define HH   8
#define DHD  32
#define NW   32   // u64 mask words per row (8 groups x 4 ballot words)

typedef __attribute__((ext_vector_type(8))) short short8;
typedef __attribute__((ext_vector_type(4))) float f32x4;
typedef __attribute__((ext_vector_type(16))) float f32x16;

#if __has_builtin(__builtin_amdgcn_exp2f)
#define EXP2(x) __builtin_amdgcn_exp2f(x)
#else
#define EXP2(x) exp2f(x)
#endif

__device__ __forceinline__ unsigned int pk2(float a, float b) {
  union { __hip_bfloat162 h2; unsigned int u; } cv;
  cv.h2 = __float22bfloat162_rn(float2{a, b});   // v_cvt_pk_bf16_f32, RNE
  return cv.u;
}
__device__ __forceinline__ unsigned short f2bf(float f) {
  unsigned int u = __float_as_uint(f);
  u += 0x7fffu + ((u >> 16) & 1u);
  return (unsigned short)(u >> 16);
}

#define QSCALE (0.17677669529663687f * 1.4426950408889634f)  // 1/sqrt(32) * log2(e)

// ---------------- K0 prep: masks + qkv INTERLEAVED (2:3 mod-5) + Wo cast tail ----------------
// bid < 2560: bid%5 in {0,1} -> mask task (1024 total); {2,3,4} -> qkv task (1536 total).
// Interleave keeps memory-latency waves (mask) and MFMA waves (qkv) co-resident per CU.
// bid >= 2560: Wo fp32 -> bf16 (64 blocks).
__global__ __launch_bounds__(256) void prep(
    const float* __restrict__ adj, unsigned long long* __restrict__ Mk,
    const float* __restrict__ x, const float* __restrict__ Wq,
    const float* __restrict__ Wk, const float* __restrict__ Wv,
    unsigned short* __restrict__ Qb, unsigned short* __restrict__ Kb,
    unsigned short* __restrict__ Vt,
    const float* __restrict__ Wo, unsigned short* __restrict__ Wob) {
  __shared__ __align__(16) unsigned short Wl[32][264];   // 16.9 KB
  const int bid = blockIdx.x, tid = threadIdx.x;
  const int w = tid >> 6, lane = tid & 63;

  if (bid >= 2560) {                      // ---- Wo cast ----
    int i = (bid - 2560) * 1024 + tid * 4;
    float4 v = *(const float4*)(Wo + i);
    unsigned int p[2] = {pk2(v.x, v.y), pk2(v.z, v.w)};
    *(uint2*)(Wob + i) = *(const uint2*)p;
    return;
  }

  const int grp = bid / 5, rem = bid % 5;
  if (rem < 2) {                          // ---- masks: task id 0..1023 ----
    const int mtask = grp * 2 + rem;
    const int row = mtask * 4 + w;
    const float* rp = adj + (size_t)row * NNN + lane * 4;
    float4 vv[8];
    #pragma unroll
    for (int G = 0; G < 8; ++G)
      vv[G] = *(const float4*)(rp + G * 256);   // all 8 issued up front
    #pragma unroll
    for (int G = 0; G < 8; ++G) {
      unsigned long long b0 = __ballot(vv[G].x != 0.0f);
      unsigned long long b1 = __ballot(vv[G].y != 0.0f);
      unsigned long long b2 = __ballot(vv[G].z != 0.0f);
      unsigned long long b3 = __ballot(vv[G].w != 0.0f);
      if (lane < 4) {
        unsigned long long bs = (lane == 0) ? b0 : (lane == 1) ? b1 : (lane == 2) ? b2 : b3;
        Mk[(size_t)row * NW + G * 4 + lane] = bs;
      }
    }
  } else {                                // ---- qkv: task id 0..1535 ----
    const int t = grp * 3 + (rem - 2);
    const int y = t >> 6, rb = t & 63;
    const int mat = y >> 3, ocb = (y & 7) * 32;
    const float* Wsrc = ((mat == 0) ? Wq : (mat == 1) ? Wk : Wv) + (size_t)ocb * DIN;

    #pragma unroll
    for (int it = 0; it < 8; ++it) {
      int f4 = it * 256 + tid;
      int oc = f4 >> 6, k4 = f4 & 63;
      float4 v = *(const float4*)(Wsrc + (size_t)oc * DIN + k4 * 4);
      unsigned int p[2] = {pk2(v.x, v.y), pk2(v.z, v.w)};
      *(uint2*)&Wl[oc][k4 * 4] = *(const uint2*)p;
    }
    __syncthreads();

    const int col = lane & 15, quad = lane >> 4;
    const int row0 = rb * 64 + w * 16;

    f32x4 acc[2];
    #pragma unroll
    for (int c = 0; c < 2; ++c) acc[c] = (f32x4){0.f, 0.f, 0.f, 0.f};

    #pragma unroll
    for (int kk = 0; kk < 8; ++kk) {
      const float* xp = x + (size_t)(row0 + col) * DIN + kk * 32 + quad * 8;
      float4 a0 = *(const float4*)xp, a1 = *(const float4*)(xp + 4);
      union { short8 s; unsigned int u[4]; } af;
      af.u[0] = pk2(a0.x, a0.y); af.u[1] = pk2(a0.z, a0.w);
      af.u[2] = pk2(a1.x, a1.y); af.u[3] = pk2(a1.z, a1.w);
      #pragma unroll
      for (int c = 0; c < 2; ++c) {
        short8 bw = *(const short8*)&Wl[c * 16 + col][kk * 32 + quad * 8];
        acc[c] = __builtin_amdgcn_mfma_f32_16x16x32_bf16(af.s, bw, acc[c], 0, 0, 0);
      }
    }
    const float scale = (mat == 0) ? QSCALE : 1.0f;
    #pragma unroll
    for (int c = 0; c < 2; ++c) {
      int oc = ocb + c * 16 + col, h = oc >> 5, dh = oc & 31;
      #pragma unroll
      for (int r = 0; r < 4; ++r) {
        int row = row0 + quad * 4 + r;
        int b = row >> 11, n = row & (NNN - 1);
        unsigned short val = f2bf(acc[c][r] * scale);
        if (mat == 2)       Vt[((size_t)(b * HH + h) * DHD + dh) * NNN + n] = val;
        else if (mat == 0)  Qb[((size_t)(b * HH + h) * NNN + n) * DHD + dh] = val;
        else                Kb[((size_t)(b * HH + h) * NNN + n) * DHD + dh] = val;
      }
    }
  }
}

// ---------------- K1: fused masked attention (R11 version) ----------------
__global__ __launch_bounds__(512, 4) void attn(
    const unsigned short* __restrict__ Qb, const unsigned short* __restrict__ Kb,
    const unsigned short* __restrict__ Vt, const unsigned long long* __restrict__ Mk,
    unsigned short* __restrict__ AOb) {
  __shared__ float OL[8][32][33];
  __shared__ float LL[8][32];
  const int tid = threadIdx.x;
  const int w = tid >> 6, lane = tid & 63;
  const int qi = lane & 31, hi = lane >> 5;
  const int bid = blockIdx.x;
  const int xcd = bid & 7, j = bid >> 3;
  const int bh = xcd * 2 + (j >> 6);       // 2 bh per XCD
  const int qt = j & 63;
  const int b = bh >> 3, h = bh & 7;
  const int q = qt * 32 + qi;
  const int k0 = w * 256;

  const unsigned short* qp = Qb + ((size_t)bh * NNN + q) * DHD + hi * 8;
  const short8 bq0 = *(const short8*)qp;
  const short8 bq1 = *(const short8*)(qp + 16);

  f32x16 accA, accB;
  #pragma unroll
  for (int i = 0; i < 16; ++i) { accA[i] = 0.f; accB[i] = 0.f; }
  float lsum = 0.f;

  const unsigned long long* mrow = Mk + ((size_t)b * NNN + q) * NW + w * 4;
  unsigned int mlo[4], mhi2[4];
  #pragma unroll
  for (int c = 0; c < 4; ++c) {
    unsigned long long mh = mrow[c] >> hi;
    mlo[c]  = (unsigned int)mh;
    mhi2[c] = (unsigned int)(mh >> 32);
  }

  const unsigned short* kbase = Kb + ((size_t)bh * NNN + k0 + qi) * DHD + hi * 8;  // qi = key
  const unsigned short* vbase = Vt + ((size_t)bh * DHD + qi) * NNN + k0 + hi * 8;  // qi = dh

  short8 ak0 = *(const short8*)(kbase);
  short8 ak1 = *(const short8*)(kbase + 16);
  short8 av0 = *(const short8*)(vbase);
  short8 av1 = *(const short8*)(vbase + 16);

  #pragma unroll
  for (int sub = 0; sub < 8; ++sub) {
    const short8 cak0 = ak0, cak1 = ak1, cav0 = av0, cav1 = av1;
    if (sub < 7) {
      const int kn = (sub + 1) * 32;
      ak0 = *(const short8*)(kbase + (size_t)kn * DHD);
      ak1 = *(const short8*)(kbase + (size_t)kn * DHD + 16);
      av0 = *(const short8*)(vbase + kn);
      av1 = *(const short8*)(vbase + kn + 16);
    }

    f32x16 z;
    #pragma unroll
    for (int i = 0; i < 16; ++i) z[i] = 0.f;
    f32x16 st = __builtin_amdgcn_mfma_f32_32x32x16_bf16(cak0, bq0, z, 0, 0, 0);
    st = __builtin_amdgcn_mfma_f32_32x32x16_bf16(cak1, bq1, st, 0, 0, 0);

    unsigned int pk[4][2];
    float gs[4];
    #pragma unroll
    for (int g = 0; g < 4; ++g) {
      float pv[4];
      #pragma unroll
      for (int r = 0; r < 4; ++r) {
        unsigned int mwd = (sub < 4) ? mlo[r] : mhi2[r];
        const int pos = (sub & 3) * 8 + g * 2;
        int msk = ((int)(mwd << (31 - pos))) >> 31;
        float e = EXP2(st[g * 4 + r]);
        pv[r] = __uint_as_float(__float_as_uint(e) & (unsigned int)msk);
      }
      gs[g] = (pv[0] + pv[1]) + (pv[2] + pv[3]);
      pk[g][0] = pk2(pv[0], pv[1]);
      pk[g][1] = pk2(pv[2], pv[3]);
    }
    lsum += (gs[0] + gs[1]) + (gs[2] + gs[3]);

    unsigned int x00 = __shfl_xor((int)pk[0][0], 32, 64), x01 = __shfl_xor((int)pk[0][1], 32, 64);
    unsigned int x10 = __shfl_xor((int)pk[1][0], 32, 64), x11 = __shfl_xor((int)pk[1][1], 32, 64);
    unsigned int x20 = __shfl_xor((int)pk[2][0], 32, 64), x21 = __shfl_xor((int)pk[2][1], 32, 64);
    unsigned int x30 = __shfl_xor((int)pk[3][0], 32, 64), x31 = __shfl_xor((int)pk[3][1], 32, 64);

    union { short8 s; unsigned int u[4]; } F1, F2;
    F1.u[0] = hi ? x10 : pk[0][0];
    F1.u[1] = hi ? x11 : pk[0][1];
    F1.u[2] = hi ? pk[1][0] : x00;
    F1.u[3] = hi ? pk[1][1] : x01;
    F2.u[0] = hi ? x30 : pk[2][0];
    F2.u[1] = hi ? x31 : pk[2][1];
    F2.u[2] = hi ? pk[3][0] : x20;
    F2.u[3] = hi ? pk[3][1] : x21;

    accA = __builtin_amdgcn_mfma_f32_32x32x16_bf16(cav0, F1.s, accA, 0, 0, 0);
    accB = __builtin_amdgcn_mfma_f32_32x32x16_bf16(cav1, F2.s, accB, 0, 0, 0);
  }

  lsum += __shfl_xor(lsum, 32, 64);

  #pragma unroll
  for (int g = 0; g < 4; ++g)
    #pragma unroll
    for (int r = 0; r < 4; ++r)
      OL[w][qi][g * 8 + hi * 4 + r] = accA[g * 4 + r] + accB[g * 4 + r];
  if (hi == 0) LL[w][qi] = lsum;
  __syncthreads();

  const int ql = tid >> 4, c2 = (tid & 15) * 2;
  float l = 0.f, o0 = 0.f, o1 = 0.f;
  #pragma unroll
  for (int ww = 0; ww < 8; ++ww) {
    l  += LL[ww][ql];
    o0 += OL[ww][ql][c2];
    o1 += OL[ww][ql][c2 + 1];
  }
  float inv = 1.0f / l;
  unsigned int pr = pk2(o0 * inv, o1 * inv);
  *(unsigned int*)(AOb + ((size_t)(b * NNN + qt * 32 + ql)) * DIN + h * DHD + c2) = pr;
}

// ---------------- K2: output projection + bias via bf16 MFMA (R10 version) ----------------
__global__ __launch_bounds__(256) void out_proj(const unsigned short* __restrict__ AOb,
                                                const unsigned short* __restrict__ Wob,
                                                const float* __restrict__ bo,
                                                float* __restrict__ out) {
  const int tid = threadIdx.x;
  const int lane = tid & 63, col = lane & 15, quad = lane >> 4;
  const int task = blockIdx.x * 4 + (tid >> 6);    // 1024 tasks
  const int row0 = (task >> 2) * 16;
  const int ocb = (task & 3) * 64;

  f32x4 acc[4];
  #pragma unroll
  for (int c = 0; c < 4; ++c) acc[c] = (f32x4){0.f, 0.f, 0.f, 0.f};

  #pragma unroll
  for (int kk = 0; kk < 8; ++kk) {
    short8 af = *(const short8*)(AOb + (size_t)(row0 + col) * DIN + kk * 32 + quad * 8);
    #pragma unroll
    for (int c = 0; c < 4; ++c) {
      short8 bw = *(const short8*)(Wob + (size_t)(ocb + c * 16 + col) * DIN + kk * 32 + quad * 8);
      acc[c] = __builtin_amdgcn_mfma_f32_16x16x32_bf16(af, bw, acc[c], 0, 0, 0);
    }
  }
  #pragma unroll
  for (int c = 0; c < 4; ++c) {
    int oc = ocb + c * 16 + col;
    float bias = bo[oc];
    #pragma unroll
    for (int r = 0; r < 4; ++r)
      out[(size_t)(row0 + quad * 4 + r) * DIN + oc] = acc[c][r] + bias;
  }
}

extern "C" void kernel_launch(void* const* d_in, const int* in_sizes, int n_in,
                              void* d_out, int out_size, void* d_ws, size_t ws_size,
                              hipStream_t stream) {
  const float* x   = (const float*)d_in[0];
  const float* adj = (const float*)d_in[1];
  const float* Wq  = (const float*)d_in[2];
  const float* Wk  = (const float*)d_in[3];
  const float* Wv  = (const float*)d_in[4];
  const float* Wo  = (const float*)d_in[5];
  const float* bo  = (const float*)d_in[6];
  float* out = (float*)d_out;

  char* ws = (char*)d_ws;
  unsigned short* Qb  = (unsigned short*)(ws);                         // 2 MB
  unsigned short* Kb  = (unsigned short*)(ws + (2ull << 20));          // 2 MB
  unsigned short* Vt  = (unsigned short*)(ws + (4ull << 20));          // 2 MB
  unsigned long long* Mk = (unsigned long long*)(ws + (6ull << 20));   // 1 MB
  unsigned short* Wob = (unsigned short*)(ws + (7ull << 20));          // 128 KB
  unsigned short* AOb = (unsigned short*)(ws + (8ull << 20));          // 2 MB

  prep<<<dim3(2624), 256, 0, stream>>>(adj, Mk, x, Wq, Wk, Wv, Qb, Kb, Vt, Wo, Wob);
  attn<<<dim3(1024), 512, 0, stream>>>(Qb, Kb, Vt, Mk, AOb);
  out_proj<<<dim3(256), 256, 0, stream>>>(AOb, Wob, bo, out);
}